// Round 21
// baseline (174.553 us; speedup 1.0000x reference)
//
#include <hip/hip_runtime.h>
#include <hip/hip_fp16.h>

static inline int idiv_up(long a, long b) { return (int)((a + b - 1) / b); }

#define RADIAL_G 2048
#define GBASE    (119 << 7)   // float-bits>>16 for exponent 119 (d = 2^-8)
#define MAXDEG   64           // fixed CSR stride; Poisson(16) tail @64 ~ 1e-22

typedef _Float16 h2 __attribute__((ext_vector_type(2)));

__device__ __forceinline__ unsigned pack_h2(float a, float b) {
    __half2 t = __floats2half2_rn(a, b);
    return *reinterpret_cast<unsigned*>(&t);
}
__device__ __forceinline__ unsigned pack_h1(float a) {
    __half t = __float2half_rn(a);
    return (unsigned)*reinterpret_cast<unsigned short*>(&t);
}
__device__ __forceinline__ h2 as_h2(unsigned u) {
    return *reinterpret_cast<h2*>(&u);
}
__device__ __forceinline__ _Float16 as_h1(unsigned u) {
    unsigned short s = (unsigned short)u;
    return *reinterpret_cast<_Float16*>(&s);
}
__device__ __forceinline__ float dot2(h2 a, h2 b) {
#if __has_builtin(__builtin_amdgcn_fdot2)
    return __builtin_amdgcn_fdot2(a, b, 0.f, false);   // v_dot2_f32_f16
#else
    return (float)a.x * (float)b.x + (float)a.y * (float)b.y;
#endif
}

// DPP cross-lane on the VALU pipe (no DS traffic).
template <int CTRL>
__device__ __forceinline__ float dppf(float x) {
    return __int_as_float(__builtin_amdgcn_update_dpp(
        0, __float_as_int(x), CTRL, 0xF, 0xF, true));
}
// all-lane sum within each 16-lane row
__device__ __forceinline__ float row_allsum(float p) {
    p += dppf<0xB1>(p);    // quad_perm xor1
    p += dppf<0x4E>(p);    // quad_perm xor2
    p += dppf<0x124>(p);   // row_ror:4
    p += dppf<0x128>(p);   // row_ror:8
    return p;
}

// ---------------------------------------------------------------------------
// Kernel 1 (3-way block-range fusion, all dependency-free):
//   [0, FOLD_B):            fold weights
//   [FOLD_B, +tabB):        radial table over log-spaced d bins
//   [FOLD_B+tabB, +posB):   pos -> 16B-aligned float4 table (1 line/gather)
// ---------------------------------------------------------------------------
#define FOLD_B 42
__global__ __launch_bounds__(256) void fold_tab_pos(
    const float* __restrict__ W_emb, const float* __restrict__ b_emb,
    const float* __restrict__ Wq, const float* __restrict__ Wk,
    const float* __restrict__ Wv0,
    float* __restrict__ Wcomb, float* __restrict__ bcomb,
    const float* __restrict__ R1, const float* __restrict__ b1,
    const float* __restrict__ R2, const float* __restrict__ b2,
    unsigned* __restrict__ TAB,
    const float* __restrict__ pos, float4* __restrict__ pos4,
    int Nn, int tabB)
{
    if (blockIdx.x < FOLD_B) {
        int idx = blockIdx.x * 256 + threadIdx.x;
        if (idx >= 33 * 320) return;
        int row = idx / 320, j = idx - row * 320;
        float acc = 0.f;
        for (int c = 0; c < 64; ++c) {
            float w;
            if (j < 128)      { int h = j >> 5,         k = j & 31;         w = Wq [(h * 64 + c) * 32 + k]; }
            else if (j < 256) { int h = (j - 128) >> 5, k = (j - 128) & 31; w = Wk [(h * 64 + c) * 32 + k]; }
            else              { int h = (j - 256) >> 4, v = (j - 256) & 15; w = Wv0[(h * 64 + c) * 16 + v]; }
            float lhs = (row < 32) ? W_emb[row * 64 + c] : b_emb[c];
            acc += lhs * w;
        }
        if (row < 32) Wcomb[row * 320 + j] = acc;
        else          bcomb[j] = acc;
        return;
    }
    int bx = (int)blockIdx.x - FOLD_B;
    if (bx < tabB) {
        int idx = bx * 256 + threadIdx.x;
        if (idx >= RADIAL_G * 64) return;
        int g = idx >> 6, lane = idx & 63;
        int h = lane >> 4, j = lane & 15;
        float d = __uint_as_float(((unsigned)(g + GBASE) << 16) | 0x8000u);
        float rh[16];
#pragma unroll
        for (int r = 0; r < 16; ++r) {
            float x = fmaf(d, R1[h * 16 + r], b1[h * 16 + r]);
            rh[r] = x / (1.f + __expf(-x));
        }
        float rk0 = b2[h * 64 + j], rk1 = b2[h * 64 + j + 16], rv = b2[h * 64 + 32 + j];
#pragma unroll
        for (int r = 0; r < 16; ++r) {
            const float* row = R2 + (size_t)(h * 16 + r) * 64;
            rk0 = fmaf(rh[r], row[j], rk0);
            rk1 = fmaf(rh[r], row[j + 16], rk1);
            rv  = fmaf(rh[r], row[32 + j], rv);
        }
        const float rs = 0.17677669529663687f * 1.4426950408889634f; // /sqrt32 * log2e
        TAB[(size_t)g * 128 + 2 * lane]     = pack_h2(rk0 * rs, rk1 * rs);
        TAB[(size_t)g * 128 + 2 * lane + 1] = pack_h1(rv);
        return;
    }
    bx -= tabB;
    {
        int n = bx * 256 + threadIdx.x;
        if (n >= Nn) return;
        float4 v;
        v.x = pos[(size_t)n * 3 + 0];
        v.y = pos[(size_t)n * 3 + 1];
        v.z = pos[(size_t)n * 3 + 2];
        v.w = 0.f;
        pos4[n] = v;
    }
}

// ---------------------------------------------------------------------------
// Kernel 2 (fused by block range, scatter first):
//   [0, edge2B):        fixed-stride CSR scatter, 2 edges/thread, float4 pos
//   [edge2B, +qkvB):    per-node tables (R15 body: one chunk/block, uniform
//                       scalar weight loads)
// ---------------------------------------------------------------------------
__global__ __launch_bounds__(256) void qkv_scatter(
    const float* __restrict__ nf, const float* __restrict__ Wcomb,
    const float* __restrict__ bcomb, unsigned* __restrict__ Qt,
    unsigned* __restrict__ KVt,
    const float4* __restrict__ pos4, const int* __restrict__ ei,
    int* __restrict__ cursor, unsigned* __restrict__ csrp,
    int Nn, int Ee, int edge2B)
{
    if ((int)blockIdx.x < edge2B) {
        int base = (int)blockIdx.x * 512 + threadIdx.x;
        int e0 = base, e1 = base + 256;
        bool v0 = e0 < Ee, v1 = e1 < Ee;
        int s0 = 0, d0 = 0, s1 = 0, d1 = 0;
        if (v0) { s0 = ei[e0]; d0 = ei[Ee + e0]; }
        if (v1) { s1 = ei[e1]; d1 = ei[Ee + e1]; }
        float dd0 = 0.f, dd1 = 0.f;
        if (v0) {
            float4 a = pos4[d0], b = pos4[s0];
            float dx = a.x - b.x, dy = a.y - b.y, dz = a.z - b.z;
            dd0 = sqrtf(dx * dx + dy * dy + dz * dz) + 1e-8f;
        }
        if (v1) {
            float4 a = pos4[d1], b = pos4[s1];
            float dx = a.x - b.x, dy = a.y - b.y, dz = a.z - b.z;
            dd1 = sqrtf(dx * dx + dy * dy + dz * dz) + 1e-8f;
        }
        if (v0) {
            int g = (__float_as_int(dd0) >> 16) - GBASE;
            g = min(max(g, 0), RADIAL_G - 1);
            int r = atomicAdd(&cursor[d0], 1);
            if (r < MAXDEG)
                csrp[((size_t)d0 << 6) + r] = (unsigned)s0 | ((unsigned)g << 20);
        }
        if (v1) {
            int g = (__float_as_int(dd1) >> 16) - GBASE;
            g = min(max(g, 0), RADIAL_G - 1);
            int r = atomicAdd(&cursor[d1], 1);
            if (r < MAXDEG)
                csrp[((size_t)d1 << 6) + r] = (unsigned)s1 | ((unsigned)g << 20);
        }
        return;
    }
    // ---- qkv branch (R15-proven body) ----
    int bx   = (int)blockIdx.x - edge2B;
    int c    = bx % 10;
    int tile = bx / 10;
    int n = tile * 256 + threadIdx.x;
    bool valid = n < Nn;
    int nc = valid ? n : (Nn - 1);

    float nfv[32];
    const float4* nfp = (const float4*)(nf + (size_t)nc * 32);
#pragma unroll
    for (int f4 = 0; f4 < 8; ++f4) {
        float4 v = nfp[f4];
        nfv[f4 * 4 + 0] = v.x; nfv[f4 * 4 + 1] = v.y;
        nfv[f4 * 4 + 2] = v.z; nfv[f4 * 4 + 3] = v.w;
    }
    const float* Wc = Wcomb + c * 32;
    float acc[32];
#pragma unroll
    for (int j4 = 0; j4 < 8; ++j4) {
        float4 b = *(const float4*)&bcomb[c * 32 + j4 * 4];   // uniform
        acc[j4 * 4 + 0] = b.x; acc[j4 * 4 + 1] = b.y;
        acc[j4 * 4 + 2] = b.z; acc[j4 * 4 + 3] = b.w;
    }
#pragma unroll
    for (int f = 0; f < 32; ++f) {
        float x = nfv[f];
        const float* row = Wc + f * 320;
#pragma unroll
        for (int j4 = 0; j4 < 8; ++j4) {
            float4 w = *(const float4*)&row[j4 * 4];          // uniform -> s_load
            acc[j4 * 4 + 0] = fmaf(x, w.x, acc[j4 * 4 + 0]);
            acc[j4 * 4 + 1] = fmaf(x, w.y, acc[j4 * 4 + 1]);
            acc[j4 * 4 + 2] = fmaf(x, w.z, acc[j4 * 4 + 2]);
            acc[j4 * 4 + 3] = fmaf(x, w.w, acc[j4 * 4 + 3]);
        }
    }
    if (!valid) return;
    if (c < 4) {
        unsigned* qp = Qt + (size_t)n * 64 + c * 16;
#pragma unroll
        for (int jj = 0; jj < 16; ++jj)
            qp[jj] = pack_h2(acc[jj], acc[jj + 16]);
    } else if (c < 8) {
        unsigned* kp = KVt + ((size_t)n << 7) + (c - 4) * 16;
#pragma unroll
        for (int jj = 0; jj < 16; ++jj)
            kp[jj] = pack_h2(acc[jj], acc[jj + 16]);
    } else {
        unsigned short* vp = (unsigned short*)(KVt + ((size_t)n << 7) + 64) + (c - 8) * 32;
#pragma unroll
        for (int jj = 0; jj < 32; ++jj)
            vp[jj] = (unsigned short)pack_h1(acc[jj]);
    }
}

// ---------------------------------------------------------------------------
// Kernel 3: fused per-node attention — ONE WAVE PER NODE, direct node index
// (no LPT perm: deg ~ Poisson(16), 12+ waves/SIMD average out the tails).
// Fixed-stride CSR: start = n<<6. Copy-free 3-buffer rotation pipeline,
// packed csr (src|g<<20), <<7 record addressing, exp2 (log2e pre-folded).
// 128-thread blocks (2 waves). Lane: h=lane>>4, j=lane&15.
// ---------------------------------------------------------------------------
struct Pair {
    unsigned ku0, vu0, ku1, vu1;
    uint2 tb0, tb1;
};

__global__ __launch_bounds__(128) void node_attn(
    const unsigned* __restrict__ Qt, const unsigned* __restrict__ KVt,
    const uint2* __restrict__ TAB, const unsigned* __restrict__ csrp,
    const int* __restrict__ cursor, const int* __restrict__ batch,
    float* __restrict__ pooled, int Nn)
{
    int lane = threadIdx.x & 63;
    int n = blockIdx.x * 2 + (threadIdx.x >> 6);
    if (n >= Nn) return;
    int cnt = min(cursor[n], MAXDEG);
    if (cnt == 0) return;
    int start = n << 6;

    h2 qh = as_h2(Qt[(size_t)n * 64 + lane]);
    float l = 0.f, acc = 0.f;

    auto LD1 = [&](int ei, unsigned& ku, unsigned& vu, uint2& tb) {
        unsigned pk = csrp[ei];
        unsigned src = pk & 0xFFFFFu;
        unsigned g   = pk >> 20;
        tb = TAB[((size_t)g << 6) + lane];
        const unsigned* kb = KVt + ((size_t)src << 7);
        ku = kb[lane];
        vu = (unsigned)((const unsigned short*)(kb + 64))[lane];
    };
    auto LDP = [&](Pair& P, int ei) {
        LD1(ei,     P.ku0, P.vu0, P.tb0);
        LD1(ei + 1, P.ku1, P.vu1, P.tb1);
    };
    auto CMP1 = [&](unsigned ku, unsigned vu, uint2 tb) {
        h2 prod = as_h2(ku) * as_h2(tb.x);             // v_pk_mul_f16
        float p = dot2(qh, prod);                       // v_dot2_f32_f16
        p = row_allsum(p);
        float ex = exp2f(fminf(p, 110.f));              // log2e pre-folded
        l += ex;
        float w = (float)(as_h1(vu) * as_h1(tb.y));
        acc = fmaf(ex, w, acc);
    };
    auto CMP = [&](const Pair& P) {
        CMP1(P.ku0, P.vu0, P.tb0);
        CMP1(P.ku1, P.vu1, P.tb1);
    };

    int e = start, end = start + cnt;
    Pair A, B, C;
    if (e + 5 < end) {
        LDP(A, e); LDP(B, e + 2); LDP(C, e + 4);
        for (; e + 11 < end; e += 6) {
            CMP(A); LDP(A, e + 6);
            CMP(B); LDP(B, e + 8);
            CMP(C); LDP(C, e + 10);
        }
        CMP(A); CMP(B); CMP(C);
        e += 6;
    }
    for (; e + 1 < end; e += 2) { LDP(A, e); CMP(A); }
    if (e < end) {
        unsigned ku, vu; uint2 tb;
        LD1(e, ku, vu, tb);
        CMP1(ku, vu, tb);
    }
    float o = acc / (l + 1e-30f);
    atomicAdd(&pooled[(size_t)batch[n] * 64 + lane], o);
}

// ---------------------------------------------------------------------------
// Kernel 4: out[b][o] = sum_i pooled[b][i] * Wproj[i][o]
// ---------------------------------------------------------------------------
__global__ __launch_bounds__(256) void final_proj(
    const float* __restrict__ pooled, const float* __restrict__ Wproj,
    float* __restrict__ out, int total)
{
    int idx = blockIdx.x * 256 + threadIdx.x;
    if (idx >= total) return;
    int b = idx >> 6, o = idx & 63;
    float acc = 0.f;
#pragma unroll
    for (int i = 0; i < 64; ++i) acc += pooled[b * 64 + i] * Wproj[i * 64 + o];
    out[idx] = acc;
}

extern "C" void kernel_launch(void* const* d_in, const int* in_sizes, int n_in,
                              void* d_out, int out_size, void* d_ws, size_t ws_size,
                              hipStream_t stream)
{
    const float* pos   = (const float*)d_in[0];
    const float* nf    = (const float*)d_in[1];
    const int*   ei    = (const int*)d_in[2];
    const int*   batch = (const int*)d_in[3];
    const float* W_emb = (const float*)d_in[4];
    const float* b_emb = (const float*)d_in[5];
    const float* Wq    = (const float*)d_in[6];
    const float* Wk    = (const float*)d_in[7];
    const float* Wv0   = (const float*)d_in[8];
    const float* R1    = (const float*)d_in[10];
    const float* b1    = (const float*)d_in[11];
    const float* R2    = (const float*)d_in[12];
    const float* b2    = (const float*)d_in[13];
    const float* Wproj = (const float*)d_in[14];
    float* out = (float*)d_out;

    long Nn = in_sizes[0] / 3;
    long Ee = in_sizes[2] / 2;
    int  Bb = out_size / 64;

    float* ws = (float*)d_ws;
    size_t o = 0;
    size_t WCOMB = o; o += 32 * 320;
    size_t BCOMB = o; o += 320;
    size_t QTAB  = o; o += (size_t)Nn * 64;      // u32 half2 per lane
    size_t KVT   = o; o += (size_t)Nn * 128;     // padded record, addr = n<<7
    size_t CURS  = o; o += (size_t)Nn;           // ---- zero region start ----
    size_t POOL  = o; o += (size_t)Bb * 64;      // ---- zero region end ----
    size_t CSR   = o; o += (size_t)Nn * MAXDEG;  // fixed-stride u32 CSR
    o = (o + 3) & ~(size_t)3;                    // 16B-align pos4/TAB
    size_t POS4  = o; o += (size_t)Nn * 4;       // float4 per node
    size_t TAB   = o; o += (size_t)RADIAL_G * 128;

    // zero cursor + pooled (contiguous)
    hipMemsetAsync(ws + CURS, 0,
                   ((size_t)Nn + (size_t)Bb * 64) * sizeof(float), stream);

    int edge2B = idiv_up(Ee, 512);
    int nodeB  = idiv_up(Nn, 256);
    int tabB   = idiv_up(RADIAL_G * 64, 256);
    int qkvB   = nodeB * 10;

    fold_tab_pos<<<FOLD_B + tabB + nodeB, 256, 0, stream>>>(
        W_emb, b_emb, Wq, Wk, Wv0, ws + WCOMB, ws + BCOMB,
        R1, b1, R2, b2, (unsigned*)(ws + TAB),
        pos, (float4*)(ws + POS4), (int)Nn, tabB);

    qkv_scatter<<<edge2B + qkvB, 256, 0, stream>>>(
        nf, ws + WCOMB, ws + BCOMB, (unsigned*)(ws + QTAB),
        (unsigned*)(ws + KVT), (const float4*)(ws + POS4), ei,
        (int*)(ws + CURS), (unsigned*)(ws + CSR), (int)Nn, (int)Ee, edge2B);

    node_attn<<<idiv_up(Nn, 2), 128, 0, stream>>>(
        (const unsigned*)(ws + QTAB), (const unsigned*)(ws + KVT),
        (const uint2*)(ws + TAB), (const unsigned*)(ws + CSR),
        (const int*)(ws + CURS), batch, ws + POOL, (int)Nn);

    final_proj<<<idiv_up(out_size, 256), 256, 0, stream>>>(
        ws + POOL, Wproj, out, out_size);
}

// Round 22
// 156.496 us; speedup vs baseline: 1.1154x; 1.1154x over previous
//
#include <hip/hip_runtime.h>
#include <hip/hip_fp16.h>

static inline int idiv_up(long a, long b) { return (int)((a + b - 1) / b); }

#define RADIAL_G 2048
#define GBASE    (119 << 7)   // float-bits>>16 for exponent 119 (d = 2^-8)
#define MAXDEG   64           // fixed CSR stride; Poisson(16) tail @64 ~ 1e-22

typedef _Float16 h2 __attribute__((ext_vector_type(2)));

__device__ __forceinline__ unsigned pack_h2(float a, float b) {
    __half2 t = __floats2half2_rn(a, b);
    return *reinterpret_cast<unsigned*>(&t);
}
__device__ __forceinline__ unsigned pack_h1(float a) {
    __half t = __float2half_rn(a);
    return (unsigned)*reinterpret_cast<unsigned short*>(&t);
}
__device__ __forceinline__ h2 as_h2(unsigned u) {
    return *reinterpret_cast<h2*>(&u);
}
__device__ __forceinline__ _Float16 as_h1(unsigned u) {
    unsigned short s = (unsigned short)u;
    return *reinterpret_cast<_Float16*>(&s);
}
__device__ __forceinline__ float dot2(h2 a, h2 b) {
#if __has_builtin(__builtin_amdgcn_fdot2)
    return __builtin_amdgcn_fdot2(a, b, 0.f, false);   // v_dot2_f32_f16
#else
    return (float)a.x * (float)b.x + (float)a.y * (float)b.y;
#endif
}

// DPP cross-lane on the VALU pipe (no DS traffic).
template <int CTRL>
__device__ __forceinline__ float dppf(float x) {
    return __int_as_float(__builtin_amdgcn_update_dpp(
        0, __float_as_int(x), CTRL, 0xF, 0xF, true));
}
// all-lane sum within each 16-lane row
__device__ __forceinline__ float row_allsum(float p) {
    p += dppf<0xB1>(p);    // quad_perm xor1
    p += dppf<0x4E>(p);    // quad_perm xor2
    p += dppf<0x124>(p);   // row_ror:4
    p += dppf<0x128>(p);   // row_ror:8
    return p;
}

// ---------------------------------------------------------------------------
// Kernel 1 (fused by block range): fold weights | radial table (both dep-free)
//   TAB[g][64] uint2: .x = half2(rk0*rs*log2e, rk1*rs*log2e), .y = f16 rv
// ---------------------------------------------------------------------------
#define FOLD_B 42
__global__ __launch_bounds__(256) void fold_tab(
    const float* __restrict__ W_emb, const float* __restrict__ b_emb,
    const float* __restrict__ Wq, const float* __restrict__ Wk,
    const float* __restrict__ Wv0,
    float* __restrict__ Wcomb, float* __restrict__ bcomb,
    const float* __restrict__ R1, const float* __restrict__ b1,
    const float* __restrict__ R2, const float* __restrict__ b2,
    unsigned* __restrict__ TAB)
{
    if (blockIdx.x < FOLD_B) {
        int idx = blockIdx.x * 256 + threadIdx.x;
        if (idx >= 33 * 320) return;
        int row = idx / 320, j = idx - row * 320;
        float acc = 0.f;
        for (int c = 0; c < 64; ++c) {
            float w;
            if (j < 128)      { int h = j >> 5,         k = j & 31;         w = Wq [(h * 64 + c) * 32 + k]; }
            else if (j < 256) { int h = (j - 128) >> 5, k = (j - 128) & 31; w = Wk [(h * 64 + c) * 32 + k]; }
            else              { int h = (j - 256) >> 4, v = (j - 256) & 15; w = Wv0[(h * 64 + c) * 16 + v]; }
            float lhs = (row < 32) ? W_emb[row * 64 + c] : b_emb[c];
            acc += lhs * w;
        }
        if (row < 32) Wcomb[row * 320 + j] = acc;
        else          bcomb[j] = acc;
        return;
    }
    {
        int idx = ((int)blockIdx.x - FOLD_B) * 256 + threadIdx.x;
        if (idx >= RADIAL_G * 64) return;
        int g = idx >> 6, lane = idx & 63;
        int h = lane >> 4, j = lane & 15;
        float d = __uint_as_float(((unsigned)(g + GBASE) << 16) | 0x8000u);
        float rh[16];
#pragma unroll
        for (int r = 0; r < 16; ++r) {
            float x = fmaf(d, R1[h * 16 + r], b1[h * 16 + r]);
            rh[r] = x / (1.f + __expf(-x));
        }
        float rk0 = b2[h * 64 + j], rk1 = b2[h * 64 + j + 16], rv = b2[h * 64 + 32 + j];
#pragma unroll
        for (int r = 0; r < 16; ++r) {
            const float* row = R2 + (size_t)(h * 16 + r) * 64;
            rk0 = fmaf(rh[r], row[j], rk0);
            rk1 = fmaf(rh[r], row[j + 16], rk1);
            rv  = fmaf(rh[r], row[32 + j], rv);
        }
        const float rs = 0.17677669529663687f * 1.4426950408889634f; // /sqrt32 * log2e
        TAB[(size_t)g * 128 + 2 * lane]     = pack_h2(rk0 * rs, rk1 * rs);
        TAB[(size_t)g * 128 + 2 * lane + 1] = pack_h1(rv);
    }
}

// ---------------------------------------------------------------------------
// Kernel 2 (fused by block range):
//   [0, qkvB):        per-node tables (R15 body: one chunk/block, uniform
//                     scalar weight loads)
//   [qkvB, +edgeB):   fixed-stride CSR scatter: r = atomicAdd(cursor[dst]);
//                     csr[dst*64 + r] = src | g<<20. Atomic latency hides
//                     under co-resident qkv blocks.
// ---------------------------------------------------------------------------
__global__ __launch_bounds__(256) void qkv_scatter(
    const float* __restrict__ nf, const float* __restrict__ Wcomb,
    const float* __restrict__ bcomb, unsigned* __restrict__ Qt,
    unsigned* __restrict__ KVt,
    const float* __restrict__ pos, const int* __restrict__ ei,
    int* __restrict__ cursor, unsigned* __restrict__ csrp,
    int Nn, int Ee, int qkvB)
{
    if ((int)blockIdx.x >= qkvB) {
        int e = ((int)blockIdx.x - qkvB) * 256 + threadIdx.x;
        if (e >= Ee) return;
        int s  = ei[e];
        int dg = ei[Ee + e];
        float dx = pos[(size_t)dg * 3 + 0] - pos[(size_t)s * 3 + 0];
        float dy = pos[(size_t)dg * 3 + 1] - pos[(size_t)s * 3 + 1];
        float dz = pos[(size_t)dg * 3 + 2] - pos[(size_t)s * 3 + 2];
        float d = sqrtf(dx * dx + dy * dy + dz * dz) + 1e-8f;
        int g = (__float_as_int(d) >> 16) - GBASE;
        g = min(max(g, 0), RADIAL_G - 1);
        int r = atomicAdd(&cursor[dg], 1);
        if (r < MAXDEG)
            csrp[((size_t)dg << 6) + r] = (unsigned)s | ((unsigned)g << 20);
        return;
    }
    // ---- qkv branch (R15-proven body) ----
    int c    = blockIdx.x % 10;
    int tile = blockIdx.x / 10;
    int n = tile * 256 + threadIdx.x;
    bool valid = n < Nn;
    int nc = valid ? n : (Nn - 1);          // clamp: keep loads in-bounds

    float nfv[32];
    const float4* nfp = (const float4*)(nf + (size_t)nc * 32);
#pragma unroll
    for (int f4 = 0; f4 < 8; ++f4) {
        float4 v = nfp[f4];
        nfv[f4 * 4 + 0] = v.x; nfv[f4 * 4 + 1] = v.y;
        nfv[f4 * 4 + 2] = v.z; nfv[f4 * 4 + 3] = v.w;
    }
    const float* Wc = Wcomb + c * 32;
    float acc[32];
#pragma unroll
    for (int j4 = 0; j4 < 8; ++j4) {
        float4 b = *(const float4*)&bcomb[c * 32 + j4 * 4];   // uniform
        acc[j4 * 4 + 0] = b.x; acc[j4 * 4 + 1] = b.y;
        acc[j4 * 4 + 2] = b.z; acc[j4 * 4 + 3] = b.w;
    }
#pragma unroll
    for (int f = 0; f < 32; ++f) {
        float x = nfv[f];
        const float* row = Wc + f * 320;
#pragma unroll
        for (int j4 = 0; j4 < 8; ++j4) {
            float4 w = *(const float4*)&row[j4 * 4];          // uniform -> s_load
            acc[j4 * 4 + 0] = fmaf(x, w.x, acc[j4 * 4 + 0]);
            acc[j4 * 4 + 1] = fmaf(x, w.y, acc[j4 * 4 + 1]);
            acc[j4 * 4 + 2] = fmaf(x, w.z, acc[j4 * 4 + 2]);
            acc[j4 * 4 + 3] = fmaf(x, w.w, acc[j4 * 4 + 3]);
        }
    }
    if (!valid) return;
    if (c < 4) {
        unsigned* qp = Qt + (size_t)n * 64 + c * 16;
#pragma unroll
        for (int jj = 0; jj < 16; ++jj)
            qp[jj] = pack_h2(acc[jj], acc[jj + 16]);
    } else if (c < 8) {
        unsigned* kp = KVt + ((size_t)n << 7) + (c - 4) * 16;
#pragma unroll
        for (int jj = 0; jj < 16; ++jj)
            kp[jj] = pack_h2(acc[jj], acc[jj + 16]);
    } else {
        unsigned short* vp = (unsigned short*)(KVt + ((size_t)n << 7) + 64) + (c - 8) * 32;
#pragma unroll
        for (int jj = 0; jj < 32; ++jj)
            vp[jj] = (unsigned short)pack_h1(acc[jj]);
    }
}

// ---------------------------------------------------------------------------
// Kernel 3: degree histogram from cursor (LDS-first, 1 global atomic/bucket/blk)
// ---------------------------------------------------------------------------
__global__ __launch_bounds__(256) void calc_hist(
    const int* __restrict__ cursor, int* __restrict__ ghist, int Nn)
{
    __shared__ int lh[128];
    if (threadIdx.x < 128) lh[threadIdx.x] = 0;
    __syncthreads();
    int n = blockIdx.x * 256 + threadIdx.x;
    if (n < Nn) {
        int d = min(cursor[n], MAXDEG);
        atomicAdd(&lh[d], 1);
    }
    __syncthreads();
    if (threadIdx.x < 128 && lh[threadIdx.x])
        atomicAdd(&ghist[threadIdx.x], lh[threadIdx.x]);
}

// ---------------------------------------------------------------------------
// Kernel 4: descending-bucket bases. bcur[b] = sum_{b'>b} ghist[b'].
// ---------------------------------------------------------------------------
__global__ __launch_bounds__(128) void bin_scan(
    const int* __restrict__ ghist, int* __restrict__ bcur)
{
    __shared__ int s[128];
    s[threadIdx.x] = ghist[threadIdx.x];
    __syncthreads();
    int sum = 0;
    for (int b = threadIdx.x + 1; b < 128; ++b) sum += s[b];
    bcur[threadIdx.x] = sum;
}

// ---------------------------------------------------------------------------
// Kernel 5: perm counting-sort scatter (deg descending -> LPT order)
// ---------------------------------------------------------------------------
__global__ __launch_bounds__(256) void perm_scatter(
    const int* __restrict__ cursor, int* __restrict__ bcur,
    int* __restrict__ perm, int Nn)
{
    __shared__ int lh[128], lbase[128];
    if (threadIdx.x < 128) lh[threadIdx.x] = 0;
    __syncthreads();
    int n = blockIdx.x * 256 + threadIdx.x;
    int bk = -1, r = 0;
    if (n < Nn) {
        bk = min(cursor[n], MAXDEG);
        r = atomicAdd(&lh[bk], 1);
    }
    __syncthreads();
    if (threadIdx.x < 128 && lh[threadIdx.x])
        lbase[threadIdx.x] = atomicAdd(&bcur[threadIdx.x], lh[threadIdx.x]);
    __syncthreads();
    if (n < Nn) perm[lbase[bk] + r] = n;
}

// ---------------------------------------------------------------------------
// Kernel 6: fused per-node attention — ONE WAVE PER NODE via LPT-sorted perm
// (R16/R18-proven schedule). Fixed-stride CSR: start = n<<6, no offs array.
// Copy-free 3-buffer rotation pipeline, packed csr (src|g<<20), <<7 record
// addressing, exp2 (log2e pre-folded). 128-thread blocks (2 waves).
// Lane: h=lane>>4, j=lane&15.
// ---------------------------------------------------------------------------
struct Pair {
    unsigned ku0, vu0, ku1, vu1;
    uint2 tb0, tb1;
};

__global__ __launch_bounds__(128) void node_attn(
    const unsigned* __restrict__ Qt, const unsigned* __restrict__ KVt,
    const uint2* __restrict__ TAB, const unsigned* __restrict__ csrp,
    const int* __restrict__ cursor, const int* __restrict__ batch,
    const int* __restrict__ perm, float* __restrict__ pooled, int Nn)
{
    int lane = threadIdx.x & 63;
    int wv = blockIdx.x * 2 + (threadIdx.x >> 6);
    if (wv >= Nn) return;
    int n = perm[wv];
    int cnt = min(cursor[n], MAXDEG);
    if (cnt == 0) return;
    int start = n << 6;

    h2 qh = as_h2(Qt[(size_t)n * 64 + lane]);
    float l = 0.f, acc = 0.f;

    auto LD1 = [&](int ei, unsigned& ku, unsigned& vu, uint2& tb) {
        unsigned pk = csrp[ei];
        unsigned src = pk & 0xFFFFFu;
        unsigned g   = pk >> 20;
        tb = TAB[((size_t)g << 6) + lane];
        const unsigned* kb = KVt + ((size_t)src << 7);
        ku = kb[lane];
        vu = (unsigned)((const unsigned short*)(kb + 64))[lane];
    };
    auto LDP = [&](Pair& P, int ei) {
        LD1(ei,     P.ku0, P.vu0, P.tb0);
        LD1(ei + 1, P.ku1, P.vu1, P.tb1);
    };
    auto CMP1 = [&](unsigned ku, unsigned vu, uint2 tb) {
        h2 prod = as_h2(ku) * as_h2(tb.x);             // v_pk_mul_f16
        float p = dot2(qh, prod);                       // v_dot2_f32_f16
        p = row_allsum(p);
        float ex = exp2f(fminf(p, 110.f));              // log2e pre-folded
        l += ex;
        float w = (float)(as_h1(vu) * as_h1(tb.y));
        acc = fmaf(ex, w, acc);
    };
    auto CMP = [&](const Pair& P) {
        CMP1(P.ku0, P.vu0, P.tb0);
        CMP1(P.ku1, P.vu1, P.tb1);
    };

    int e = start, end = start + cnt;
    Pair A, B, C;
    if (e + 5 < end) {
        LDP(A, e); LDP(B, e + 2); LDP(C, e + 4);
        for (; e + 11 < end; e += 6) {
            CMP(A); LDP(A, e + 6);
            CMP(B); LDP(B, e + 8);
            CMP(C); LDP(C, e + 10);
        }
        CMP(A); CMP(B); CMP(C);
        e += 6;
    }
    for (; e + 1 < end; e += 2) { LDP(A, e); CMP(A); }
    if (e < end) {
        unsigned ku, vu; uint2 tb;
        LD1(e, ku, vu, tb);
        CMP1(ku, vu, tb);
    }
    float o = acc / (l + 1e-30f);
    atomicAdd(&pooled[(size_t)batch[n] * 64 + lane], o);
}

// ---------------------------------------------------------------------------
// Kernel 7: out[b][o] = sum_i pooled[b][i] * Wproj[i][o]
// ---------------------------------------------------------------------------
__global__ __launch_bounds__(256) void final_proj(
    const float* __restrict__ pooled, const float* __restrict__ Wproj,
    float* __restrict__ out, int total)
{
    int idx = blockIdx.x * 256 + threadIdx.x;
    if (idx >= total) return;
    int b = idx >> 6, o = idx & 63;
    float acc = 0.f;
#pragma unroll
    for (int i = 0; i < 64; ++i) acc += pooled[b * 64 + i] * Wproj[i * 64 + o];
    out[idx] = acc;
}

extern "C" void kernel_launch(void* const* d_in, const int* in_sizes, int n_in,
                              void* d_out, int out_size, void* d_ws, size_t ws_size,
                              hipStream_t stream)
{
    const float* pos   = (const float*)d_in[0];
    const float* nf    = (const float*)d_in[1];
    const int*   ei    = (const int*)d_in[2];
    const int*   batch = (const int*)d_in[3];
    const float* W_emb = (const float*)d_in[4];
    const float* b_emb = (const float*)d_in[5];
    const float* Wq    = (const float*)d_in[6];
    const float* Wk    = (const float*)d_in[7];
    const float* Wv0   = (const float*)d_in[8];
    const float* R1    = (const float*)d_in[10];
    const float* b1    = (const float*)d_in[11];
    const float* R2    = (const float*)d_in[12];
    const float* b2    = (const float*)d_in[13];
    const float* Wproj = (const float*)d_in[14];
    float* out = (float*)d_out;

    long Nn = in_sizes[0] / 3;
    long Ee = in_sizes[2] / 2;
    int  Bb = out_size / 64;

    float* ws = (float*)d_ws;
    size_t o = 0;
    size_t WCOMB = o; o += 32 * 320;
    size_t BCOMB = o; o += 320;
    size_t QTAB  = o; o += (size_t)Nn * 64;      // u32 half2 per lane
    size_t KVT   = o; o += (size_t)Nn * 128;     // padded record, addr = n<<7
    size_t CURS  = o; o += (size_t)Nn;           // ---- zero region start ----
    size_t GHIST = o; o += 128;
    size_t POOL  = o; o += (size_t)Bb * 64;      // ---- zero region end ----
    size_t BCUR  = o; o += 128;
    size_t PERM  = o; o += (size_t)Nn;
    size_t CSR   = o; o += (size_t)Nn * MAXDEG;  // fixed-stride u32 CSR
    o = (o + 1) & ~(size_t)1;                    // 8B-align TAB (uint2)
    size_t TAB   = o; o += (size_t)RADIAL_G * 128;

    // zero cursor + ghist + pooled (contiguous)
    hipMemsetAsync(ws + CURS, 0,
                   ((size_t)Nn + 128 + (size_t)Bb * 64) * sizeof(float), stream);

    int edgeB = idiv_up(Ee, 256);
    int nodeB = idiv_up(Nn, 256);
    int tabB  = idiv_up(RADIAL_G * 64, 256);
    int qkvB  = nodeB * 10;

    fold_tab<<<FOLD_B + tabB, 256, 0, stream>>>(
        W_emb, b_emb, Wq, Wk, Wv0, ws + WCOMB, ws + BCOMB,
        R1, b1, R2, b2, (unsigned*)(ws + TAB));

    qkv_scatter<<<qkvB + edgeB, 256, 0, stream>>>(
        nf, ws + WCOMB, ws + BCOMB, (unsigned*)(ws + QTAB),
        (unsigned*)(ws + KVT), pos, ei,
        (int*)(ws + CURS), (unsigned*)(ws + CSR), (int)Nn, (int)Ee, qkvB);

    calc_hist<<<nodeB, 256, 0, stream>>>(
        (const int*)(ws + CURS), (int*)(ws + GHIST), (int)Nn);

    bin_scan<<<1, 128, 0, stream>>>(
        (const int*)(ws + GHIST), (int*)(ws + BCUR));

    perm_scatter<<<nodeB, 256, 0, stream>>>(
        (const int*)(ws + CURS), (int*)(ws + BCUR), (int*)(ws + PERM), (int)Nn);

    node_attn<<<idiv_up(Nn, 2), 128, 0, stream>>>(
        (const unsigned*)(ws + QTAB), (const unsigned*)(ws + KVT),
        (const uint2*)(ws + TAB), (const unsigned*)(ws + CSR),
        (const int*)(ws + CURS), batch, (const int*)(ws + PERM),
        ws + POOL, (int)Nn);

    final_proj<<<idiv_up(out_size, 256), 256, 0, stream>>>(
        ws + POOL, Wproj, out, out_size);
}